// Round 6
// baseline (133.697 us; speedup 1.0000x reference)
//
#include <hip/hip_runtime.h>
#include <hip/hip_fp16.h>

#define N_NODES 50000
#define N_EDGES 1600000
#define D 48

#define EPB 8192            // edges per prep block
#define PB  196             // ceil(N_EDGES/EPB)
#define NPB_D 50            // dst-bin size: 1000 bins exactly, balanced 4/CU grid
#define NBIN_D 1000

#define HB 128              // hist blocks; 1600000/128 = 12500 edges/slice exactly
#define ESL (N_EDGES / HB)  // 12500
#define HW ((N_NODES + 3) / 4)   // 12500 packed u32 words (4x u8 counters)

#define EMAX 2400           // per-dst-bin edge cap (mean 1600, sigma ~40 -> 20 sigma)
#define HS 52               // h/W LDS stride (16B-aligned, bank-spread; proven R10)
#define SFS 64              // sfeat row stride in halves: 128 B = one aligned L2 line

// ---------- workspace layout (bytes) ----------
#define RECD_OFF  0          // u32[PB*EPB] block-major: (src<<6)|dlocal -> end 6,422,528
#define OFFLD_OFF 6422528    // u16[PB][NBIN_D+1]          -> end 6,814,920
#define CNT_OFF   6814920    // u32[HB][HW] packed byte counters -> end 13,214,920
#define CI_OFF    13214920   // f32[50000]                 -> end 13,414,920
#define SFEAT_OFF 13415040   // f16[50000*64], 128B-aligned, rounded UP past ci
                             // (R5 bug: rounding DOWN aliased ci[49998..49999]
                             //  -> k_ci write race -> nondeterministic output)
#define SFEAT_END 19815040

// Out-degree histogram: 128 blocks, each histograms its 12500-edge slice into
// 50000 8-bit counters packed 4/u32 in 48.8 KB LDS, then flushes coalesced.
__global__ __launch_bounds__(512) void k_hist(const int* __restrict__ src,
                                              unsigned int* __restrict__ cnts) {
    __shared__ unsigned int hw[HW];     // 50 KB packed counters
    int tid = threadIdx.x, blk = blockIdx.x;
    for (int i = tid; i < HW; i += 512) hw[i] = 0;
    __syncthreads();
    const int4* s4 = (const int4*)(src + blk * ESL);   // ESL%4==0
    for (int i = tid; i < ESL / 4; i += 512) {
        int4 v = s4[i];
        atomicAdd(&hw[v.x >> 2], 1u << ((v.x & 3) * 8));
        atomicAdd(&hw[v.y >> 2], 1u << ((v.y & 3) * 8));
        atomicAdd(&hw[v.z >> 2], 1u << ((v.z & 3) * 8));
        atomicAdd(&hw[v.w >> 2], 1u << ((v.w & 3) * 8));
    }
    __syncthreads();
    unsigned int* o = cnts + (size_t)blk * HW;
    for (int i = tid; i < HW; i += 512) o[i] = hw[i];
}

// Merge 128 byte-counters per node -> ci = rsqrt(max(deg,1)); fused fp16
// prescale into LINE-PADDED rows (128 B: 48 data halves + 16 zero pad).
// Pad must be re-zeroed every call (harness re-poisons the workspace).
__global__ __launch_bounds__(512) void k_ci(const unsigned int* __restrict__ cnts,
                                            const float* __restrict__ feat,
                                            float* __restrict__ ci,
                                            __half* __restrict__ sfeat,
                                            int do_scale) {
    int n = blockIdx.x * 512 + threadIdx.x;
    if (n >= N_NODES) return;
    int w = n >> 2, sh = (n & 3) * 8;
    unsigned int s = 0;
    #pragma unroll 8
    for (int b = 0; b < HB; ++b) s += (cnts[(size_t)b * HW + w] >> sh) & 0xFFu;
    float c = rsqrtf(fmaxf((float)s, 1.0f));
    ci[n] = c;
    if (do_scale) {
        const float4* f4 = (const float4*)feat + (size_t)n * 12;
        uint4* o4 = (uint4*)(sfeat + (size_t)n * SFS);
        #pragma unroll
        for (int k = 0; k < 6; ++k) {
            float4 fa = f4[k * 2];
            float4 fb = f4[k * 2 + 1];
            __half2 h0 = __float22half2_rn(make_float2(fa.x * c, fa.y * c));
            __half2 h1 = __float22half2_rn(make_float2(fa.z * c, fa.w * c));
            __half2 h2 = __float22half2_rn(make_float2(fb.x * c, fb.y * c));
            __half2 h3 = __float22half2_rn(make_float2(fb.z * c, fb.w * c));
            o4[k] = make_uint4(*(unsigned int*)&h0, *(unsigned int*)&h1,
                               *(unsigned int*)&h2, *(unsigned int*)&h3);
        }
        o4[6] = make_uint4(0, 0, 0, 0);     // zero pad: lanes 6,7 of each
        o4[7] = make_uint4(0, 0, 0, 0);     // edge-slot accumulate these
    }
}

// Dst counting-sort: count + scan + scatter, all block-local; coalesced output.
__global__ __launch_bounds__(1024) void k_prep(const int* __restrict__ src,
                                               const int* __restrict__ dst,
                                               unsigned int* __restrict__ rec,
                                               unsigned short* __restrict__ offld) {
    __shared__ int cd[NBIN_D];                  // histogram, then cursor
    __shared__ int wsum[16], wexcl[16];
    __shared__ alignas(16) unsigned int bufd[EPB];
    int tid = threadIdx.x, p = blockIdx.x;
    int wave = tid >> 6, lane = tid & 63;
    int base = p * EPB;

    // int4 edge loads: N_EDGES%4==0 and EPB%4==0 -> quads never straddle the
    // valid tail, so per-quad masking is exact.
    int sv[8], dv[8];
    bool ok[8];
    const int4* s4p = (const int4*)src;
    const int4* d4p = (const int4*)dst;
    #pragma unroll
    for (int c = 0; c < 2; ++c) {
        int e4 = base + c * 4096 + tid * 4;
        bool v = (e4 < N_EDGES);
        int4 s4 = v ? s4p[e4 >> 2] : make_int4(0, 0, 0, 0);
        int4 d4 = v ? d4p[e4 >> 2] : make_int4(0, 0, 0, 0);
        sv[c * 4 + 0] = s4.x; sv[c * 4 + 1] = s4.y;
        sv[c * 4 + 2] = s4.z; sv[c * 4 + 3] = s4.w;
        dv[c * 4 + 0] = d4.x; dv[c * 4 + 1] = d4.y;
        dv[c * 4 + 2] = d4.z; dv[c * 4 + 3] = d4.w;
        ok[c * 4 + 0] = v; ok[c * 4 + 1] = v; ok[c * 4 + 2] = v; ok[c * 4 + 3] = v;
    }

    for (int i = tid; i < NBIN_D; i += 1024) cd[i] = 0;
    __syncthreads();
    #pragma unroll
    for (int k = 0; k < 8; ++k) {
        if (ok[k]) atomicAdd(&cd[dv[k] / NPB_D], 1);
    }
    __syncthreads();

    // wave-shuffle scan over cd (1000 elements, threads 0..999)
    int own = (tid < NBIN_D) ? cd[tid] : 0;
    int incl = own;
    #pragma unroll
    for (int o = 1; o < 64; o <<= 1) {
        int u = __shfl_up(incl, o);
        if (lane >= o) incl += u;
    }
    if (lane == 63) wsum[wave] = incl;
    __syncthreads();
    if (tid < 16) {
        int v = wsum[tid];
        int ic = v;
        #pragma unroll
        for (int o = 1; o < 16; o <<= 1) {
            int u = __shfl_up(ic, o);
            if (lane >= o) ic += u;
        }
        wexcl[tid] = ic - v;
    }
    __syncthreads();
    if (tid < NBIN_D) {
        int gincl = wexcl[wave] + incl;
        int ex = gincl - own;
        offld[p * (NBIN_D + 1) + tid] = (unsigned short)ex;
        cd[tid] = ex;                           // cursor
        if (tid == NBIN_D - 1) offld[p * (NBIN_D + 1) + NBIN_D] = (unsigned short)gincl;
    }
    __syncthreads();

    #pragma unroll
    for (int k = 0; k < 8; ++k) {
        if (ok[k]) {
            int s = sv[k], d = dv[k];
            int bin = d / NPB_D;
            int pd = atomicAdd(&cd[bin], 1);
            bufd[pd] = ((unsigned int)s << 6) | (unsigned int)(d - bin * NPB_D);
        }
    }
    __syncthreads();

    // coalesced full-line stream out
    int4* ro = (int4*)(rec + base);
    const int4* bi = (const int4*)bufd;
    for (int i = tid; i < EPB / 4; i += 1024) ro[i] = bi[i];
}

// Fused CSR-build + gather + GEMM: one block (8 waves, 512 thr) per 50-node bin.
// 1000 blocks, 4 blocks/CU -> all co-resident, balanced makespan.
template <bool PRESCALED>
__global__ __launch_bounds__(512, 8) void k_gcn(
    const unsigned int* __restrict__ rec, const unsigned short* __restrict__ offld,
    const float* __restrict__ ci, const __half* __restrict__ sfeat,
    const float* __restrict__ feat,
    const float* __restrict__ W, const float* __restrict__ b,
    float* __restrict__ out) {
    __shared__ int   colb[EMAX];        // 9.6 KB reordered local col (src ids)
    __shared__ float hl[NPB_D * HS];    // 10.4 KB
    __shared__ float Wl[D * HS];        // 10.0 KB
    __shared__ float bl[D];
    __shared__ int   ideg[NPB_D];
    __shared__ int   off[NPB_D];
    __shared__ int   cur[NPB_D];
    __shared__ int   runoff[PB + 1];
    __shared__ int   runpos[PB];
    __shared__ int   wsum[8], wexcl[8];
    int tid = threadIdx.x, bin = blockIdx.x;
    int wave = tid >> 6, lane = tid & 63;

    for (int i = tid; i < D * D; i += 512) Wl[(i / D) * HS + (i % D)] = W[i];
    if (tid < D) bl[tid] = b[tid];
    if (tid < NPB_D) { ideg[tid] = 0; cur[tid] = 0; }

    // ---- run table + wave-shuffle scan of run lengths ----
    int rlen = 0;
    if (tid < PB) {
        int o0 = offld[tid * (NBIN_D + 1) + bin];
        int o1 = offld[tid * (NBIN_D + 1) + bin + 1];
        rlen = o1 - o0;
        runpos[tid] = tid * EPB + o0;
    }
    int incl = rlen;
    #pragma unroll
    for (int o = 1; o < 64; o <<= 1) {
        int u = __shfl_up(incl, o);
        if (lane >= o) incl += u;
    }
    if (lane == 63) wsum[wave] = incl;
    __syncthreads();
    if (tid < 8) {
        int v = wsum[tid];
        int ic = v;
        #pragma unroll
        for (int o = 1; o < 8; o <<= 1) {
            int u = __shfl_up(ic, o);
            if (lane >= o) ic += u;
        }
        wexcl[tid] = ic - v;
        if (tid == 7) runoff[PB] = ic;
    }
    __syncthreads();
    if (tid < PB) runoff[tid] = wexcl[wave] + incl - rlen;
    __syncthreads();
    int cnt = runoff[PB];
    if (cnt > EMAX) cnt = EMAX;         // unreachable; guards LDS OOB

    // ---- Phase A: gather runs into regs (binary search), histogram, scan, reorder ----
    unsigned int rr[5];
    #pragma unroll
    for (int k = 0; k < 5; ++k) {
        int j = tid + k * 512;
        rr[k] = 0xFFFFFFFFu;
        if (j < cnt) {
            int lo = 0, hi = PB - 1;
            while (lo < hi) {
                int mid = (lo + hi + 1) >> 1;
                if (runoff[mid] <= j) lo = mid; else hi = mid - 1;
            }
            unsigned int r = rec[runpos[lo] + (j - runoff[lo])];
            rr[k] = r;
            atomicAdd(&ideg[r & 63], 1);
        }
    }
    __syncthreads();
    if (tid < NPB_D) {
        int v = ideg[tid];
        int ic = v;
        #pragma unroll
        for (int o = 1; o < 64; o <<= 1) {
            int u = __shfl_up(ic, o);
            if (tid >= o) ic += u;
        }
        off[tid] = ic - v;
    }
    __syncthreads();
    #pragma unroll
    for (int k = 0; k < 5; ++k) {
        if (rr[k] != 0xFFFFFFFFu) {
            int dl = rr[k] & 63;
            int p = atomicAdd(&cur[dl], 1);
            colb[off[dl] + p] = (int)(rr[k] >> 6);
        }
    }
    __syncthreads();

    // ---- Phase B: line-aligned gather; node nl = q*8 + wave (wave-uniform) ----
    // PRESCALED rows are 128 B aligned: 8 slots x 8 lanes, each lane one uint4
    // -> exactly ONE L2 line per edge (R4 theory: Phase B is line-transaction
    // bound; 96 B unaligned rows cost ~1.75 lines/edge). Lanes 6,7 read the
    // zeroed pad from the SAME line and accumulate zeros (no mask, no traffic).
    int eslot = lane >> 3;              // 0..7
    int d8 = lane & 7;                  // 0..7
    const float4* feat4 = (const float4*)feat;
    const uint4* sf = (const uint4*)sfeat;   // 8 units per 128-B row

    for (int q = 0; q < 7; ++q) {
        int nl = q * 8 + wave;
        if (nl >= NPB_D) break;         // wave-uniform
        int n = bin * NPB_D + nl;
        int cb = off[nl];
        int deg = ideg[nl];

        float4 accA = make_float4(0.0f, 0.0f, 0.0f, 0.0f);
        float4 accB = make_float4(0.0f, 0.0f, 0.0f, 0.0f);
        if (PRESCALED) {
            for (int i0 = 0; i0 < deg; i0 += 8) {
                int ei = i0 + eslot;
                bool act = (ei < deg);
                int s = act ? colb[cb + ei] : 0;
                if (act) {
                    uint4 u = sf[(size_t)s * 8 + d8];
                    __half2 h0 = *reinterpret_cast<__half2*>(&u.x);
                    __half2 h1 = *reinterpret_cast<__half2*>(&u.y);
                    __half2 h2 = *reinterpret_cast<__half2*>(&u.z);
                    __half2 h3 = *reinterpret_cast<__half2*>(&u.w);
                    float2 f0 = __half22float2(h0);
                    float2 f1 = __half22float2(h1);
                    float2 f2 = __half22float2(h2);
                    float2 f3 = __half22float2(h3);
                    accA.x += f0.x; accA.y += f0.y; accA.z += f1.x; accA.w += f1.y;
                    accB.x += f2.x; accB.y += f2.y; accB.z += f3.x; accB.w += f3.y;
                }
            }
        } else {
            bool lane_ok = (d8 < 6);
            for (int i0 = 0; i0 < deg; i0 += 8) {
                int ei = i0 + eslot;
                bool act = lane_ok && (ei < deg);
                int s = act ? colb[cb + ei] : 0;
                if (act) {
                    float c = ci[s];
                    float4 fa = feat4[(size_t)s * 12 + d8 * 2];
                    float4 fb = feat4[(size_t)s * 12 + d8 * 2 + 1];
                    accA.x = fmaf(fa.x, c, accA.x);
                    accA.y = fmaf(fa.y, c, accA.y);
                    accA.z = fmaf(fa.z, c, accA.z);
                    accA.w = fmaf(fa.w, c, accA.w);
                    accB.x = fmaf(fb.x, c, accB.x);
                    accB.y = fmaf(fb.y, c, accB.y);
                    accB.z = fmaf(fb.z, c, accB.z);
                    accB.w = fmaf(fb.w, c, accB.w);
                }
            }
        }
        // reduce 8 edge slots: xor-tree over lane bits 3..5 (slot index)
        #pragma unroll
        for (int m = 8; m <= 32; m <<= 1) {
            accA.x += __shfl_xor(accA.x, m);
            accA.y += __shfl_xor(accA.y, m);
            accA.z += __shfl_xor(accA.z, m);
            accA.w += __shfl_xor(accA.w, m);
            accB.x += __shfl_xor(accB.x, m);
            accB.y += __shfl_xor(accB.y, m);
            accB.z += __shfl_xor(accB.z, m);
            accB.w += __shfl_xor(accB.w, m);
        }
        if (lane < 6) {                 // slot 0, d8 = lane
            float4 rA, rB;
            if (deg > 0) {
                float cj = rsqrtf((float)deg);
                rA = make_float4(accA.x * cj, accA.y * cj, accA.z * cj, accA.w * cj);
                rB = make_float4(accB.x * cj, accB.y * cj, accB.z * cj, accB.w * cj);
            } else {
                rA = feat4[(size_t)n * 12 + lane * 2];
                rB = feat4[(size_t)n * 12 + lane * 2 + 1];
            }
            *(float4*)(hl + nl * HS + lane * 8) = rA;
            *(float4*)(hl + nl * HS + lane * 8 + 4) = rB;
        }
    }
    __syncthreads();

    // ---- Phase C: out = relu(h @ W^T + b), b128 LDS reads; 2 node-halves ----
    #pragma unroll
    for (int half = 0; half < 2; ++half) {
        int nl = (tid >> 4) + half * 32;
        int c = tid & 15;               // od = c, c+16, c+32
        if (nl < NPB_D) {
            int n = bin * NPB_D + nl;
            float a0 = bl[c], a1 = bl[c + 16], a2 = bl[c + 32];
            #pragma unroll
            for (int k4 = 0; k4 < 12; ++k4) {
                float4 hv = *(const float4*)(hl + nl * HS + k4 * 4);
                float4 w0 = *(const float4*)(Wl + c * HS + k4 * 4);
                float4 w1 = *(const float4*)(Wl + (c + 16) * HS + k4 * 4);
                float4 w2 = *(const float4*)(Wl + (c + 32) * HS + k4 * 4);
                a0 = fmaf(hv.x, w0.x, a0); a0 = fmaf(hv.y, w0.y, a0);
                a0 = fmaf(hv.z, w0.z, a0); a0 = fmaf(hv.w, w0.w, a0);
                a1 = fmaf(hv.x, w1.x, a1); a1 = fmaf(hv.y, w1.y, a1);
                a1 = fmaf(hv.z, w1.z, a1); a1 = fmaf(hv.w, w1.w, a1);
                a2 = fmaf(hv.x, w2.x, a2); a2 = fmaf(hv.y, w2.y, a2);
                a2 = fmaf(hv.z, w2.z, a2); a2 = fmaf(hv.w, w2.w, a2);
            }
            float* op = out + (size_t)n * D;
            op[c]      = fmaxf(a0, 0.0f);
            op[c + 16] = fmaxf(a1, 0.0f);
            op[c + 32] = fmaxf(a2, 0.0f);
        }
    }
}

extern "C" void kernel_launch(void* const* d_in, const int* in_sizes, int n_in,
                              void* d_out, int out_size, void* d_ws, size_t ws_size,
                              hipStream_t stream) {
    const float* feat = (const float*)d_in[0];
    const int*   src  = (const int*)d_in[1];
    const int*   dst  = (const int*)d_in[2];
    const float* W    = (const float*)d_in[3];
    const float* b    = (const float*)d_in[4];
    float* out = (float*)d_out;

    char* ws = (char*)d_ws;
    unsigned int*   rec   = (unsigned int*)(ws + RECD_OFF);
    unsigned short* offld = (unsigned short*)(ws + OFFLD_OFF);
    unsigned int*   cnts  = (unsigned int*)(ws + CNT_OFF);
    float*          ci    = (float*)(ws + CI_OFF);
    __half*         sfeat = (__half*)(ws + SFEAT_OFF);

    const bool prescale = (ws_size >= (size_t)SFEAT_END);

    k_hist<<<HB, 512, 0, stream>>>(src, cnts);
    k_prep<<<PB, 1024, 0, stream>>>(src, dst, rec, offld);
    k_ci<<<(N_NODES + 511) / 512, 512, 0, stream>>>(cnts, feat, ci, sfeat,
                                                    prescale ? 1 : 0);
    if (prescale)
        k_gcn<true><<<NBIN_D, 512, 0, stream>>>(rec, offld, ci, sfeat, feat, W, b, out);
    else
        k_gcn<false><<<NBIN_D, 512, 0, stream>>>(rec, offld, ci, sfeat, feat, W, b, out);
}